// Round 1
// baseline (1617.530 us; speedup 1.0000x reference)
//
#include <hip/hip_runtime.h>

// Floyd-Steinberg dithering, BIT_WIDTH=1 (quant = round-half-even).
// 96 independent images (32*3) of 512x512 fp32.
// One wave (64 lanes) per image; lane l owns row 64*p + l in pass p.
// Wavefront skew: at step t, lane l processes column c = t - 2*l.
// Errors flow lane->lane+1 via __shfl_up; pass-boundary row via LDS
// double buffer with a 4-deep prefetch queue.
//
// CORRECTNESS-CRITICAL: must replicate reference fp32 ops bit-exactly:
//   up  = (W_UL*e[c-1] + W_U*e[c]) + W_UR*e[c+1]   (left-to-right adds)
//   val = min(max((x01 + up) + W_L*left, 0), 1)
//   err = val - rint(val)
// No FMA contraction allowed -> #pragma clang fp contract(off).

#define F_UL 0.0625f   // 1/16
#define F_U  0.3125f   // 5/16
#define F_UR 0.1875f   // 3/16
#define F_L  0.4375f   // 7/16

constexpr int WW     = 512;
constexpr int IMG    = 512 * 512;
constexpr int NIMG   = 96;
constexpr int PASSES = 8;   // 512 rows / 64 lanes

__global__ __launch_bounds__(64, 1)
void dither_kernel(const float* __restrict__ xin, float* __restrict__ yout) {
#pragma clang fp contract(off)
  const int img  = blockIdx.x;
  const int lane = threadIdx.x;
  const bool l0  = (lane == 0);
  const bool l63 = (lane == 63);

  // Double-buffered boundary-error row: buf[i][j+1] = err[last_row][j],
  // j in [-1, 512]; pads (idx 0 and 513) stay zero forever.
  __shared__ float buf[2][WW + 2];
  for (int i = lane; i < 2 * (WW + 2); i += 64) ((float*)buf)[i] = 0.0f;
  __syncthreads();

  const float* xi = xin + (size_t)img * IMG;
  float*       yo = yout + (size_t)img * IMG;

  for (int p = 0; p < PASSES; ++p) {
    float* bufR = buf[p & 1];        // errs of row (64p - 1), zeros for p=0
    float* bufW = buf[(p & 1) ^ 1];  // errs of row (64p + 63) -> next pass

    const int r = p * 64 + lane;
    const float* xrow = xi + r * WW;
    float*       yrow = yo + r * WW;

    float err = 0.0f;                // own left error (err[r][c-1])
    float s2  = 0.0f;                // err[r-1][c-1] tap
    // Prime the U tap for lane 0: s1 = err[r-1][0]
    float pr  = bufR[1];
    float s1  = l0 ? pr : 0.0f;      // err[r-1][c] tap

    int c = -2 * lane;               // column this lane computes at step t=0

    // LDS prefetch queue for lane 0: at step t it needs bufR[t+2]
    float q0 = bufR[2], q1 = bufR[3], q2 = bufR[4], q3 = bufR[5];

    auto step = [&](float qv) {
#pragma clang fp contract(off)
      float e_sh = __shfl_up(err, 1, 64);   // err[r-1][c+1] from lane-1
      float e_in = l0 ? qv : e_sh;

      float xr  = xrow[c & (WW - 1)];       // masked addr: always in-row
      float xc  = fminf(fmaxf(xr, -1.0f), 1.0f);
      float x01 = (xc + 1.0f) * 0.5f;       // /2.0 == *0.5, exact

      float t1  = F_UL * s2;
      float t2  = F_U  * s1;
      float t3  = F_UR * e_in;
      float u   = (t1 + t2) + t3;           // ref's left-to-right order
      float a1  = x01 + u;
      float b   = F_L * err;
      float v   = a1 + b;
      float val = fminf(fmaxf(v, 0.0f), 1.0f);
      float qn  = rintf(val);               // v_rndne: half-to-even
      float e   = val - qn;

      bool act  = (unsigned)c < (unsigned)WW;
      float en  = act ? e : 0.0f;           // inactive lanes emit 0 errs
      if (act) yrow[c] = (qn + qn) - 1.0f;  // {0,1} -> {-1,+1}, exact
      if (act & l63) bufW[c + 1] = en;      // boundary row for next pass
      err = en;
      s2 = s1;
      s1 = e_in;
      ++c;
    };

    // 640 steps covers lane 63's last column (t = 637); extra steps inert.
    for (int T = 0; T < 640; T += 4) {
      int i0 = T + 6, i1 = T + 7, i2 = T + 8, i3 = T + 9;
      float n0 = bufR[i0 > 513 ? 513 : i0];
      float n1 = bufR[i1 > 513 ? 513 : i1];
      float n2 = bufR[i2 > 513 ? 513 : i2];
      float n3 = bufR[i3 > 513 ? 513 : i3];
      step(q0); step(q1); step(q2); step(q3);
      q0 = n0; q1 = n1; q2 = n2; q3 = n3;
    }
    __syncthreads();  // LDS boundary row visible before next pass
  }
}

extern "C" void kernel_launch(void* const* d_in, const int* in_sizes, int n_in,
                              void* d_out, int out_size, void* d_ws, size_t ws_size,
                              hipStream_t stream) {
  const float* x = (const float*)d_in[0];
  float*       y = (float*)d_out;
  dither_kernel<<<dim3(NIMG), dim3(64), 0, stream>>>(x, y);
}

// Round 2
// 516.357 us; speedup vs baseline: 3.1326x; 3.1326x over previous
//
#include <hip/hip_runtime.h>

// Floyd-Steinberg dithering, BIT_WIDTH=1. 96 images of 512x512 fp32.
// One wave per image; lane l owns row 64p+l in pass p; skewed wavefront
// c = t - 2*lane. Round 2: DPP wave_shr1 for the lane-to-lane error hop,
// LDS-staged x (global_load_lds, coalesced) with register prefetch queue,
// float2-packed y stores (column parity is wave-uniform).
//
// Bit-exactness: op order matches reference; rintf = round-half-even;
// fp contract OFF in the recurrence.

#define F_UL 0.0625f   // 1/16
#define F_U  0.3125f   // 5/16
#define F_UR 0.1875f   // 3/16
#define F_L  0.4375f   // 7/16

constexpr int WW     = 512;
constexpr int IMG    = WW * WW;
constexpr int NIMG   = 96;
constexpr int PASSES = 8;
constexpr int BUFW   = 656;   // boundary-err row, zero-padded; reads up to [649]

typedef __attribute__((address_space(3))) void       lds_void;
typedef const __attribute__((address_space(1))) void g_void;

__device__ __forceinline__ float wave_shr1(float v, float fill) {
  // lane l gets v[l-1]; lane 0 keeps `fill` (old, bound_ctrl=false)
  int r = __builtin_amdgcn_update_dpp(__float_as_int(fill), __float_as_int(v),
                                      0x138 /*wave_shr:1*/, 0xF, 0xF, false);
  return __int_as_float(r);
}

__global__ __launch_bounds__(64, 1)
void dither_kernel(const float* __restrict__ xin, float* __restrict__ yout) {
  const int  img  = blockIdx.x;
  const int  lane = threadIdx.x;
  const bool l63  = (lane == 63);

  __shared__ float xs[64 * WW];     // 128 KB: current pass's 64 input rows
  __shared__ float buf[2][BUFW];    // double-buffered boundary error rows

  for (int i = lane; i < 2 * BUFW; i += 64) (&buf[0][0])[i] = 0.0f;
  __syncthreads();

  const float* xi = xin + (size_t)img * IMG;
  float*       yo = yout + (size_t)img * IMG;

  for (int p = 0; p < PASSES; ++p) {
    // ---- stage 64 rows (128 KB) of x into LDS, coalesced async ----
    const float* gsrc = xi + p * (64 * WW);
    for (int k = 0; k < 128; ++k) {
      __builtin_amdgcn_global_load_lds(
          (g_void*)(gsrc + k * 256 + lane * 4),
          (lds_void*)(xs + k * 256),
          16, 0, 0);
    }
    __syncthreads();   // drains vmcnt, then barrier

    float* bufR = buf[p & 1];
    float* bufW = buf[(p & 1) ^ 1];
    const float* xrow = xs + lane * WW;
    float*       yrow = yo + (size_t)(p * 64 + lane) * WW;

    const int c0 = -2 * lane;

    float err = 0.0f, s2 = 0.0f;
    float s1 = (lane == 0) ? bufR[1] : 0.0f;   // err[r-1][0] prime (broadcast+sel)

    // x register queue: xq0..7 = x[c0..c0+7]; r0,r1 in flight = x[c0+8..11]
    float2 i01 = *(const float2*)(xrow + ((c0 + 0) & 511));
    float2 i23 = *(const float2*)(xrow + ((c0 + 2) & 511));
    float2 i45 = *(const float2*)(xrow + ((c0 + 4) & 511));
    float2 i67 = *(const float2*)(xrow + ((c0 + 6) & 511));
    float xq0 = i01.x, xq1 = i01.y, xq2 = i23.x, xq3 = i23.y;
    float xq4 = i45.x, xq5 = i45.y, xq6 = i67.x, xq7 = i67.y;
    float2 r0 = *(const float2*)(xrow + ((c0 + 8) & 511));
    float2 r1 = *(const float2*)(xrow + ((c0 + 10) & 511));

    // boundary-row queue (lane 0's e_in source): q = bufR[T+2..T+5]
    float2 qi0 = *(const float2*)(bufR + 2);
    float2 qi1 = *(const float2*)(bufR + 4);
    float q0 = qi0.x, q1 = qi0.y, q2 = qi1.x, q3 = qi1.y;
    float2 f0 = *(const float2*)(bufR + 6);
    float2 f1 = *(const float2*)(bufR + 8);

    auto step = [&](int c, float qv, float xv) -> float {
#pragma clang fp contract(off)
      float e_in = wave_shr1(err, qv);        // err[r-1][c+1]
      float xc   = fminf(fmaxf(xv, -1.0f), 1.0f);
      float x01  = (xc + 1.0f) * 0.5f;
      float t1   = F_UL * s2;
      float t2   = F_U  * s1;
      float t3   = F_UR * e_in;
      float u    = (t1 + t2) + t3;            // ref's left-to-right order
      float a1   = x01 + u;
      float b    = F_L * err;
      float v    = a1 + b;
      float val  = fminf(fmaxf(v, 0.0f), 1.0f);
      float qn   = rintf(val);                // round-half-even
      float e    = val - qn;
      float en   = ((unsigned)c < 512u) ? e : 0.0f;
      err = en; s2 = s1; s1 = e_in;
      return (qn + qn) - 1.0f;                // {0,1} -> {-1,+1}
    };

    for (int T = 0; T < 640; T += 4) {
      const int cg = c0 + T;
      // prefetch next group's boundary-row queue (broadcast, off-chain)
      float2 g0 = *(const float2*)(bufR + (T + 10));
      float2 g1 = *(const float2*)(bufR + (T + 12));

      float y0 = step(cg + 0, q0, xq0);
      float2 n0 = *(const float2*)(xrow + ((cg + 12) & 511));
      float b0 = err;
      float y1 = step(cg + 1, q1, xq1);
      if ((unsigned)(cg + 1) < 512u) {
        *(float2*)(yrow + cg) = make_float2(y0, y1);
        if (l63) { bufW[cg + 1] = b0; bufW[cg + 2] = err; }
      }

      float y2 = step(cg + 2, q2, xq2);
      float2 n1 = *(const float2*)(xrow + ((cg + 14) & 511));
      float b2 = err;
      float y3 = step(cg + 3, q3, xq3);
      if ((unsigned)(cg + 3) < 512u) {
        *(float2*)(yrow + (cg + 2)) = make_float2(y2, y3);
        if (l63) { bufW[cg + 3] = b2; bufW[cg + 4] = err; }
      }

      // rotate queues
      xq0 = xq4; xq1 = xq5; xq2 = xq6; xq3 = xq7;
      xq4 = r0.x; xq5 = r0.y; xq6 = r1.x; xq7 = r1.y;
      r0 = n0; r1 = n1;
      q0 = f0.x; q1 = f0.y; q2 = f1.x; q3 = f1.y;
      f0 = g0; f1 = g1;
    }
    __syncthreads();  // xs dead + bufW visible before next pass
  }
}

extern "C" void kernel_launch(void* const* d_in, const int* in_sizes, int n_in,
                              void* d_out, int out_size, void* d_ws, size_t ws_size,
                              hipStream_t stream) {
  const float* x = (const float*)d_in[0];
  float*       y = (float*)d_out;
  dither_kernel<<<dim3(NIMG), dim3(64), 0, stream>>>(x, y);
}

// Round 3
// 484.276 us; speedup vs baseline: 3.3401x; 1.0662x over previous
//
#include <hip/hip_runtime.h>

// Floyd-Steinberg dithering, BIT_WIDTH=1. 96 images of 512x512 fp32.
// One wave per image; lane l owns row 64p+l in pass p; skewed wavefront
// c = t - 2*lane; lane-to-lane error hop via DPP wave_shr:1.
// Round 3: unroll-8 instruction diet. Queue rotations become SSA renames,
// LDS reads are aligned float2 with ~1-iteration prefetch distance,
// y stores are paired float2, bufW writes are branch-free (clamped addr,
// value provably 0 where clamped).
//
// Bit-exactness (validated R1/R2): op order matches reference, rintf =
// round-half-even, fp contract OFF inside the recurrence.

#define F_UL 0.0625f   // 1/16
#define F_U  0.3125f   // 5/16
#define F_UR 0.1875f   // 3/16
#define F_L  0.4375f   // 7/16

constexpr int WW      = 512;
constexpr int IMG     = WW * WW;
constexpr int NIMG    = 96;
constexpr int PASSES  = 8;
constexpr int BUFW    = 656;          // boundary-err rows; reads hit <= [649]
constexpr int XS_OFF  = 2 * BUFW;     // bufs FIRST so small negative x-prefetch
                                      // indices stay inside the allocation
constexpr int LDS_FLOATS = XS_OFF + 64 * WW + 32;  // +32 tail pad for prefetch

typedef __attribute__((address_space(3))) void       lds_void;
typedef const __attribute__((address_space(1))) void g_void;

__device__ __forceinline__ float wave_shr1(float v, float fill) {
  // lane l gets v[l-1]; lane 0 keeps `fill` (old operand, bound_ctrl=false)
  int r = __builtin_amdgcn_update_dpp(__float_as_int(fill), __float_as_int(v),
                                      0x138 /*wave_shr:1*/, 0xF, 0xF, false);
  return __int_as_float(r);
}

__global__ __launch_bounds__(64, 1)
void dither_kernel(const float* __restrict__ xin, float* __restrict__ yout) {
  __shared__ __align__(16) float lds[LDS_FLOATS];
  const int lane = threadIdx.x;
  const int img  = blockIdx.x;
  const bool l63 = (lane == 63);

  float* buf0 = lds;
  float* buf1 = lds + BUFW;
  float* xs   = lds + XS_OFF;

  for (int i = lane; i < XS_OFF; i += 64) lds[i] = 0.0f;
  __syncthreads();

  const float* xi = xin + (size_t)img * IMG;
  float*       yo = yout + (size_t)img * IMG;

  for (int p = 0; p < PASSES; ++p) {
    // ---- stage this pass's 64 rows (128 KB) into LDS, coalesced async ----
    const float* gsrc = xi + p * (64 * WW);
    for (int k = 0; k < 128; ++k) {
      __builtin_amdgcn_global_load_lds((g_void*)(gsrc + k * 256 + lane * 4),
                                       (lds_void*)(xs + k * 256), 16, 0, 0);
    }
    __syncthreads();   // drains vmcnt then barrier (R2-validated pattern)

    float* bufR = (p & 1) ? buf1 : buf0;
    float* bufW = (p & 1) ? buf0 : buf1;
    const float* xrow = xs + lane * WW;
    float*       yrow = yo + (size_t)(p * 64 + lane) * WW;
    const int    c0   = -2 * lane;

    float err = 0.0f, s2 = 0.0f;
    float s1 = (lane == 0) ? bufR[1] : 0.0f;   // err[r-1][0] prime

    // prime current queues: x[c0..c0+7] (masked), bufR[2..9]
    float2 xa = *(const float2*)(xrow + ((c0 + 0) & 511));
    float2 xb = *(const float2*)(xrow + ((c0 + 2) & 511));
    float2 xc = *(const float2*)(xrow + ((c0 + 4) & 511));
    float2 xd = *(const float2*)(xrow + ((c0 + 6) & 511));
    float2 qa = *(const float2*)(bufR + 2);
    float2 qb = *(const float2*)(bufR + 4);
    float2 qc = *(const float2*)(bufR + 6);
    float2 qd = *(const float2*)(bufR + 8);

    auto step = [&](int c, float qv, float xv) -> float {
#pragma clang fp contract(off)
      float e_in = wave_shr1(err, qv);           // err[r-1][c+1]
      float xcl  = fminf(fmaxf(xv, -1.0f), 1.0f);
      float x01  = (xcl + 1.0f) * 0.5f;
      float t1   = F_UL * s2;
      float t2   = F_U  * s1;
      float t3   = F_UR * e_in;
      float u    = (t1 + t2) + t3;               // ref's left-to-right order
      float a1   = x01 + u;
      float b    = F_L * err;
      float v    = a1 + b;
      float val  = fminf(fmaxf(v, 0.0f), 1.0f);
      float qn   = rintf(val);                   // round-half-even
      float e    = val - qn;
      float en   = ((unsigned)c < 512u) ? e : 0.0f;
      err = en; s2 = s1; s1 = e_in;
      return __builtin_fmaf(qn, 2.0f, -1.0f);    // {0,1} -> {-1,+1}, exact
    };

    for (int T = 0; T < 640; T += 8) {
      const int cg = c0 + T;
      // prefetch next iteration's queues (~8 steps of latency cover)
      float2 nxa = *(const float2*)(xrow + (cg + 8));
      float2 nxb = *(const float2*)(xrow + (cg + 10));
      float2 nxc = *(const float2*)(xrow + (cg + 12));
      float2 nxd = *(const float2*)(xrow + (cg + 14));
      float2 nqa = *(const float2*)(bufR + (T + 10));
      float2 nqb = *(const float2*)(bufR + (T + 12));
      float2 nqc = *(const float2*)(bufR + (T + 14));
      float2 nqd = *(const float2*)(bufR + (T + 16));

      float y0 = step(cg + 0, qa.x, xa.x); float e0 = err;
      float y1 = step(cg + 1, qa.y, xa.y); float e1 = err;
      float y2 = step(cg + 2, qb.x, xb.x); float e2 = err;
      float y3 = step(cg + 3, qb.y, xb.y); float e3 = err;
      float y4 = step(cg + 4, qc.x, xc.x); float e4 = err;
      float y5 = step(cg + 5, qc.y, xc.y); float e5 = err;
      float y6 = step(cg + 6, qd.x, xd.x); float e6 = err;
      float y7 = step(cg + 7, qd.y, xd.y); float e7 = err;

      // paired y stores (c even; pair active iff 0 <= c <= 510)
      if ((unsigned)(cg + 0) < 511u) *(float2*)(yrow + cg + 0) = make_float2(y0, y1);
      if ((unsigned)(cg + 2) < 511u) *(float2*)(yrow + cg + 2) = make_float2(y2, y3);
      if ((unsigned)(cg + 4) < 511u) *(float2*)(yrow + cg + 4) = make_float2(y4, y5);
      if ((unsigned)(cg + 6) < 511u) *(float2*)(yrow + cg + 6) = make_float2(y6, y7);

      // boundary row for next pass: branch-free clamped writes.
      // Where the clamp bites (c<0) the value en is exactly 0, and idx 0
      // is never read; high side (c>=512) also writes exact 0s.
      if (l63) {
        bufW[max(cg + 1, 0)] = e0;
        bufW[max(cg + 2, 0)] = e1;
        bufW[max(cg + 3, 0)] = e2;
        bufW[max(cg + 4, 0)] = e3;
        bufW[max(cg + 5, 0)] = e4;
        bufW[max(cg + 6, 0)] = e5;
        bufW[max(cg + 7, 0)] = e6;
        bufW[max(cg + 8, 0)] = e7;
      }

      // rotate queues (pure renames after unrolling)
      xa = nxa; xb = nxb; xc = nxc; xd = nxd;
      qa = nqa; qb = nqb; qc = nqc; qd = nqd;
    }
    __syncthreads();  // xs dead + bufW visible before next pass
  }
}

extern "C" void kernel_launch(void* const* d_in, const int* in_sizes, int n_in,
                              void* d_out, int out_size, void* d_ws, size_t ws_size,
                              hipStream_t stream) {
  const float* x = (const float*)d_in[0];
  float*       y = (float*)d_out;
  dither_kernel<<<dim3(NIMG), dim3(64), 0, stream>>>(x, y);
}

// Round 4
// 400.404 us; speedup vs baseline: 4.0397x; 1.2095x over previous
//
#include <hip/hip_runtime.h>

// Floyd-Steinberg dithering, BIT_WIDTH=1. 96 images of 512x512 fp32.
// Round 4: full-image wavefront across 8 waves (512 threads/block).
// Wave w owns rows 64w+lane; within a wave the R1-R3 skewed recurrence
// (c = t - 2*lane, DPP wave_shr:1 error hop) is unchanged. Wave w+1
// trails wave w, consuming its lane-63 error row from a per-wave LDS
// region, synchronized by chunked spin-flags (LDS atomics, workgroup
// scope -> lgkm-only waits; no vmcnt drains, so the global x prefetch
// pipeline stays in flight). x is read directly from global through a
// 3-iteration register queue; no __syncthreads in the main loop.
//
// Bit-exactness (validated R1-R3): op order matches reference, rintf =
// round-half-even, fp contract OFF inside the recurrence.

#define F_UL 0.0625f   // 1/16
#define F_U  0.3125f   // 5/16
#define F_UR 0.1875f   // 3/16
#define F_L  0.4375f   // 7/16

constexpr int WW   = 512;
constexpr int IMG  = WW * WW;
constexpr int NIMG = 96;
constexpr int NW   = 8;     // waves per block; wave w owns rows 64w..64w+63
constexpr int BUFW = 792;   // boundary region floats (base offset +128;
                            // writes hit [3,643], reads hit <= [785])
constexpr int NCH  = 40;    // 16-step chunks per wave (640 steps total)
constexpr int LAG  = 10;    // consumer chunk j needs producer flag >= j+LAG
                            // (skew 126 + 24-col lookahead, /16, ceil)

__device__ __forceinline__ float wave_shr1(float v, float fill) {
  // lane l gets v[l-1]; lane 0 keeps `fill` (old operand, bound_ctrl=false)
  int r = __builtin_amdgcn_update_dpp(__float_as_int(fill), __float_as_int(v),
                                      0x138 /*wave_shr:1*/, 0xF, 0xF, false);
  return __int_as_float(r);
}

__global__ __launch_bounds__(512, 1)
void dither_kernel(const float* __restrict__ xin, float* __restrict__ yout) {
  __shared__ float bnd[(NW + 1) * BUFW];  // region w: read by wave w (w=0: zeros),
                                          // written by wave w-1; region 8 = wave 7 sink
  __shared__ int flags[NW];               // chunks completed by wave w

  const int  tid  = threadIdx.x;
  const int  wave = tid >> 6;
  const int  lane = tid & 63;
  const int  img  = blockIdx.x;
  const bool l63  = (lane == 63);

  for (int i = tid; i < (NW + 1) * BUFW; i += 512) bnd[i] = 0.0f;
  if (tid < NW) flags[tid] = 0;
  __syncthreads();  // one-time; nothing in flight yet

  const int r = wave * 64 + lane;
  const float* xrow = xin + (size_t)img * IMG + (size_t)r * WW;
  float*       yrow = yout + (size_t)img * IMG + (size_t)r * WW;
  float* bufR = bnd + wave * BUFW;
  float* bufW = bnd + (wave + 1) * BUFW;
  const int c0 = -2 * lane;

  auto ldx = [&](int c) -> float2 {   // even c; & 511 keeps addr in-row
    return *(const float2*)(xrow + (c & 511));
  };
  auto pp = [](float xv) -> float {   // x -> x01, ref op order
#pragma clang fp contract(off)
    float xc = fminf(fmaxf(xv, -1.0f), 1.0f);
    return (xc + 1.0f) * 0.5f;
  };

  // ---- prime x pipeline: cols c0..c0+23 (3 iterations deep) ----
  float2 A0 = ldx(c0 + 0),  A1 = ldx(c0 + 2),  A2 = ldx(c0 + 4),  A3 = ldx(c0 + 6);
  float2 pB0 = ldx(c0 + 8),  pB1 = ldx(c0 + 10), pB2 = ldx(c0 + 12), pB3 = ldx(c0 + 14);
  float2 pC0 = ldx(c0 + 16), pC1 = ldx(c0 + 18), pC2 = ldx(c0 + 20), pC3 = ldx(c0 + 22);
  float xq0 = pp(A0.x), xq1 = pp(A0.y), xq2 = pp(A1.x), xq3 = pp(A1.y);
  float xq4 = pp(A2.x), xq5 = pp(A2.y), xq6 = pp(A3.x), xq7 = pp(A3.y);
  float2 pA0 = pB0, pA1 = pB1, pA2 = pB2, pA3 = pB3;   // raw cols +8..15
  pB0 = pC0; pB1 = pC1; pB2 = pC2; pB3 = pC3;          // raw cols +16..23

  // ---- wait for producer before touching boundary region ----
  if (wave) {
    while (__hip_atomic_load(&flags[wave - 1], __ATOMIC_ACQUIRE,
                             __HIP_MEMORY_SCOPE_WORKGROUP) < LAG)
      __builtin_amdgcn_s_sleep(1);
  }

  float err = 0.0f, s2 = 0.0f;
  float s1 = (lane == 0) ? bufR[129] : 0.0f;   // err[r-1][0] prime
  // boundary queue: q covers cols T+1..T+8 (idx T+130..137), f the next 8
  float2 qa = *(const float2*)(bufR + 130);
  float2 qb = *(const float2*)(bufR + 132);
  float2 qc = *(const float2*)(bufR + 134);
  float2 qd = *(const float2*)(bufR + 136);
  float2 fa = *(const float2*)(bufR + 138);
  float2 fb = *(const float2*)(bufR + 140);
  float2 fc = *(const float2*)(bufR + 142);
  float2 fd = *(const float2*)(bufR + 144);

  auto step = [&](int c, float qv, float xv) -> float {
#pragma clang fp contract(off)
    float e_in = wave_shr1(err, qv);          // err[r-1][c+1]
    float t1   = F_UL * s2;
    float t2   = F_U  * s1;
    float t3   = F_UR * e_in;
    float u    = (t1 + t2) + t3;              // ref's left-to-right order
    float a1   = xv + u;                      // xv = x01 (preprocessed)
    float b    = F_L * err;
    float v    = a1 + b;
    float val  = fminf(fmaxf(v, 0.0f), 1.0f);
    float qn   = rintf(val);                  // round-half-even
    float e    = val - qn;
    float en   = ((unsigned)c < 512u) ? e : 0.0f;
    err = en; s2 = s1; s1 = e_in;
    return __builtin_fmaf(qn, 2.0f, -1.0f);   // {0,1} -> {-1,+1}, exact
  };

  auto iter8 = [&](int T) {
    const int cg = c0 + T;
    // issue raw x loads for cols cg+24..31 (consumed 3 iterations later)
    float2 n0 = ldx(cg + 24), n1 = ldx(cg + 26), n2 = ldx(cg + 28), n3 = ldx(cg + 30);
    // boundary prefetch for iteration T+16 (cols T+17..T+24)
    float2 g0 = *(const float2*)(bufR + (T + 146));
    float2 g1 = *(const float2*)(bufR + (T + 148));
    float2 g2 = *(const float2*)(bufR + (T + 150));
    float2 g3 = *(const float2*)(bufR + (T + 152));
    // preprocess raw cols cg+8..15 for next iteration (off-chain)
    float w0 = pp(pA0.x), w1 = pp(pA0.y), w2 = pp(pA1.x), w3 = pp(pA1.y);
    float w4 = pp(pA2.x), w5 = pp(pA2.y), w6 = pp(pA3.x), w7 = pp(pA3.y);

    float y0 = step(cg + 0, qa.x, xq0); float e0 = err;
    float y1 = step(cg + 1, qa.y, xq1); float e1 = err;
    float y2 = step(cg + 2, qb.x, xq2); float e2 = err;
    float y3 = step(cg + 3, qb.y, xq3); float e3 = err;
    float y4 = step(cg + 4, qc.x, xq4); float e4 = err;
    float y5 = step(cg + 5, qc.y, xq5); float e5 = err;
    float y6 = step(cg + 6, qd.x, xq6); float e6 = err;
    float y7 = step(cg + 7, qd.y, xq7); float e7 = err;

    if ((unsigned)(cg + 0) < 511u) *(float2*)(yrow + cg + 0) = make_float2(y0, y1);
    if ((unsigned)(cg + 2) < 511u) *(float2*)(yrow + cg + 2) = make_float2(y2, y3);
    if ((unsigned)(cg + 4) < 511u) *(float2*)(yrow + cg + 4) = make_float2(y4, y5);
    if ((unsigned)(cg + 6) < 511u) *(float2*)(yrow + cg + 6) = make_float2(y6, y7);

    if (l63) {  // boundary row for next wave; cg+129 >= 3, no clamp needed
      float* bw = bufW + (cg + 129);
      bw[0] = e0; bw[1] = e1; bw[2] = e2; bw[3] = e3;
      bw[4] = e4; bw[5] = e5; bw[6] = e6; bw[7] = e7;
    }

    xq0 = w0; xq1 = w1; xq2 = w2; xq3 = w3;
    xq4 = w4; xq5 = w5; xq6 = w6; xq7 = w7;
    pA0 = pB0; pA1 = pB1; pA2 = pB2; pA3 = pB3;
    pB0 = n0;  pB1 = n1;  pB2 = n2;  pB3 = n3;
    qa = fa; qb = fb; qc = fc; qd = fd;
    fa = g0; fb = g1; fc = g2; fd = g3;
  };

  for (int j = 0; j < NCH; ++j) {
    if (wave) {
      int need = j + LAG; if (need > NCH) need = NCH;   // saturate: no deadlock
      while (__hip_atomic_load(&flags[wave - 1], __ATOMIC_ACQUIRE,
                               __HIP_MEMORY_SCOPE_WORKGROUP) < need)
        __builtin_amdgcn_s_sleep(1);
    }
    iter8(16 * j);
    iter8(16 * j + 8);
    if (l63)
      __hip_atomic_store(&flags[wave], j + 1, __ATOMIC_RELEASE,
                         __HIP_MEMORY_SCOPE_WORKGROUP);
  }
}

extern "C" void kernel_launch(void* const* d_in, const int* in_sizes, int n_in,
                              void* d_out, int out_size, void* d_ws, size_t ws_size,
                              hipStream_t stream) {
  const float* x = (const float*)d_in[0];
  float*       y = (float*)d_out;
  dither_kernel<<<dim3(NIMG), dim3(512), 0, stream>>>(x, y);
}